// Round 12
// baseline (238.229 us; speedup 1.0000x reference)
//
#include <hip/hip_runtime.h>
#include <hip/hip_bf16.h>

#define N 8192
#define D 1024
#define NCLS 128
#define MARGIN 1.0f
#define TSTR 132   // epilogue LDS tile stride in u16

typedef __attribute__((ext_vector_type(8))) short bf16x8;
typedef __attribute__((ext_vector_type(4))) float f32x4;
typedef __attribute__((ext_vector_type(8))) _Float16 f16x8;
typedef __attribute__((ext_vector_type(4))) _Float16 f16x4;
typedef __attribute__((ext_vector_type(8))) unsigned short u16x8;

__device__ inline unsigned short f2bf(float x) {
    unsigned u = __float_as_uint(x);
    unsigned r = (u + 0x7FFFu + ((u >> 16) & 1u)) >> 16;  // RNE
    return (unsigned short)r;
}

__device__ inline float h2f(unsigned hb) {
    return (float)__builtin_bit_cast(_Float16, (unsigned short)(hb & 0xFFFFu));
}

// decode linear id -> (a, b) with b >= a over 64x64 upper-tri tile grid
__device__ inline void tri_decode(int l, int& a, int& b) {
    int bb = (int)((sqrtf(8.0f * (float)l + 1.0f) - 1.0f) * 0.5f);
    while ((bb + 1) * (bb + 2) / 2 <= l) ++bb;
    while (bb * (bb + 1) / 2 > l) --bb;
    b = bb;
    a = l - bb * (bb + 1) / 2;
}

// Kernel 0: class histogram + prefix (1 block). Also inits out.
__global__ __launch_bounds__(256) void hist_kernel(const int* __restrict__ target,
                                                   int* __restrict__ start_g,
                                                   int* __restrict__ cursor_g,
                                                   float* __restrict__ out) {
    __shared__ int bins[NCLS];
    const int tid = threadIdx.x;
    if (tid < NCLS) bins[tid] = 0;
    __syncthreads();
    for (int j = tid; j < N; j += 256) atomicAdd(&bins[target[j]], 1);
    __syncthreads();
    if (tid == 0) {
        int acc = 0;
        for (int c = 0; c < NCLS; ++c) { start_g[c] = acc; cursor_g[c] = acc; acc += bins[c]; }
        start_g[NCLS] = acc;
        out[0] = 0.0f;
    }
}

// Kernel 1: class-sorted scatter + fp32->bf16 + per-row sumsq + per-anchor
// class range [cs,ce). Within-class order from atomics is irrelevant: per-anchor
// value sets (and hence losses) are permutation-invariant.
__global__ __launch_bounds__(256) void scatter_kernel(const float* __restrict__ E,
                                                      const int* __restrict__ target,
                                                      const int* __restrict__ start_g,
                                                      int* __restrict__ cursor_g,
                                                      unsigned short* __restrict__ Ebf,
                                                      float* __restrict__ sq,
                                                      unsigned short* __restrict__ cs16,
                                                      unsigned short* __restrict__ ce16,
                                                      unsigned* __restrict__ P32) {
    __shared__ int pos_s;
    __shared__ float red[4];
    const int r = blockIdx.x;
    const int tid = threadIdx.x;
    if (tid == 0) pos_s = atomicAdd(&cursor_g[target[r]], 1);
    __syncthreads();
    const int pos = pos_s;
    const float4 v = ((const float4*)(E + (size_t)r * D))[tid];
    ushort4 o;
    o.x = f2bf(v.x); o.y = f2bf(v.y); o.z = f2bf(v.z); o.w = f2bf(v.w);
    ((ushort4*)(Ebf + (size_t)pos * D))[tid] = o;
    float s = v.x * v.x + v.y * v.y + v.z * v.z + v.w * v.w;
    for (int off = 32; off > 0; off >>= 1) s += __shfl_down(s, off);
    const int lane = tid & 63, wave = tid >> 6;
    if (lane == 0) red[wave] = s;
    __syncthreads();
    if (tid == 0) {
        sq[pos] = red[0] + red[1] + red[2] + red[3];
        const int c = target[r];
        cs16[pos] = (unsigned short)start_g[c];
        ce16[pos] = (unsigned short)start_g[c + 1];
        P32[pos] = 0u;
    }
}

// Kernel 2 (unchanged R11): symmetric D2, upper-tri tiles, k-seg swizzled LDS,
// tile-packed contiguous store (packed rows = low tile a, cols = high tile b).
__global__ __launch_bounds__(256) void gemm_kernel(const unsigned short* __restrict__ E,
                                                   const float* __restrict__ sq,
                                                   _Float16* __restrict__ D2pk) {
    __shared__ char smem[128 * TSTR * 2];
    unsigned short* As = (unsigned short*)smem;
    unsigned short* Bs = (unsigned short*)(smem + 8192);
    _Float16* Ts = (_Float16*)smem;

    const int tid = threadIdx.x;
    const int lane = tid & 63;
    const int wave = tid >> 6;
    const int wm = wave & 1, wn = wave >> 1;

    int bx, by;
    tri_decode(blockIdx.x, bx, by);
    const int rm = by * 128;
    const int cn = bx * 128;

    const int srow = tid >> 2;
    const int rot_s = (srow >> 1) & 3;
    const int scol = (((tid & 3) + rot_s) & 3) * 8;

    const unsigned short* gA = E + (size_t)(rm + srow) * D + scol;
    const unsigned short* gB = E + (size_t)(cn + srow) * D + scol;

    f32x4 acc[4][4] = {};

    const int mr = lane & 15;
    const int kq2 = ((((lane >> 4)) - ((mr >> 1) & 3)) & 3) * 8;

    for (int k0 = 0; k0 < D; k0 += 32) {
        __builtin_amdgcn_global_load_lds(
            (const __attribute__((address_space(1))) unsigned int*)(gA + k0),
            (__attribute__((address_space(3))) unsigned int*)((char*)As + wave * 1024), 16, 0, 0);
        __builtin_amdgcn_global_load_lds(
            (const __attribute__((address_space(1))) unsigned int*)(gA + (size_t)64 * D + k0),
            (__attribute__((address_space(3))) unsigned int*)((char*)As + 4096 + wave * 1024), 16, 0, 0);
        __builtin_amdgcn_global_load_lds(
            (const __attribute__((address_space(1))) unsigned int*)(gB + k0),
            (__attribute__((address_space(3))) unsigned int*)((char*)Bs + wave * 1024), 16, 0, 0);
        __builtin_amdgcn_global_load_lds(
            (const __attribute__((address_space(1))) unsigned int*)(gB + (size_t)64 * D + k0),
            (__attribute__((address_space(3))) unsigned int*)((char*)Bs + 4096 + wave * 1024), 16, 0, 0);
        __syncthreads();

        bf16x8 af[4], bfr[4];
#pragma unroll
        for (int mi = 0; mi < 4; ++mi)
            af[mi] = *(const bf16x8*)(As + (wm * 64 + mi * 16 + mr) * 32 + kq2);
#pragma unroll
        for (int ni = 0; ni < 4; ++ni)
            bfr[ni] = *(const bf16x8*)(Bs + (wn * 64 + ni * 16 + mr) * 32 + kq2);
#pragma unroll
        for (int mi = 0; mi < 4; ++mi)
#pragma unroll
            for (int ni = 0; ni < 4; ++ni)
                acc[mi][ni] = __builtin_amdgcn_mfma_f32_16x16x32_bf16(af[mi], bfr[ni], acc[mi][ni], 0, 0, 0);
        __syncthreads();
    }

    const int crow = (lane >> 4) * 4;
    const int ccol = lane & 15;
    float sqj[4];
#pragma unroll
    for (int ni = 0; ni < 4; ++ni)
        sqj[ni] = sq[cn + wn * 64 + ni * 16 + ccol];
#pragma unroll
    for (int mi = 0; mi < 4; ++mi) {
        const int lrow = wm * 64 + mi * 16 + crow;
        const int i0 = rm + lrow;
        float sqi[4];
#pragma unroll
        for (int r = 0; r < 4; ++r) sqi[r] = sq[i0 + r];
#pragma unroll
        for (int ni = 0; ni < 4; ++ni) {
            const int lcol = wn * 64 + ni * 16 + ccol;
            f16x4 tv;
#pragma unroll
            for (int r = 0; r < 4; ++r) {
                float d2 = fmaxf(sqi[r] + sqj[ni] - 2.0f * acc[mi][ni][r], 0.0f);
                tv[r] = (_Float16)d2;
            }
            *(f16x4*)(Ts + (size_t)lcol * TSTR + lrow) = tv;
        }
    }
    __syncthreads();
#pragma unroll
    for (int it = 0; it < 8; ++it) {
        const int rt = it * 16 + (tid >> 4);
        const int seg = tid & 15;
        f16x4 v0 = *(const f16x4*)(Ts + (size_t)rt * TSTR + seg * 8);
        f16x4 v1 = *(const f16x4*)(Ts + (size_t)rt * TSTR + seg * 8 + 4);
        f16x8 v = __builtin_shufflevector(v0, v1, 0, 1, 2, 3, 4, 5, 6, 7);
        *(f16x8*)(D2pk + (size_t)blockIdx.x * 16384 + rt * 128 + seg * 8) = v;
    }
}

// Kernel 3: mineP — hardest-positive (u16 max) only; with class-sorted anchors,
// positive pairs live only in tiles whose row class-ranges intersect the tile's
// columns (~190 of 2080). Other blocks exit after a cheap test. Commits via
// u32 atomicMax (sparse, value-only -> deterministic).
__global__ __launch_bounds__(256) void mineP_kernel(const _Float16* __restrict__ D2pk,
                                                    const unsigned short* __restrict__ cs16,
                                                    const unsigned short* __restrict__ ce16,
                                                    unsigned* __restrict__ P32) {
    __shared__ unsigned short csA_l[128], ceA_l[128], csB_l[128], ceB_l[128];
    __shared__ unsigned short colP_l[4][128];
    __shared__ int anyflag;
    const int tid = threadIdx.x;
    const int lane = tid & 63, wave = tid >> 6;
    int a, b;
    tri_decode(blockIdx.x, a, b);
    if (tid == 0) anyflag = 0;
    if (tid < 128) { csA_l[tid] = cs16[a * 128 + tid]; ceA_l[tid] = ce16[a * 128 + tid]; }
    else { csB_l[tid - 128] = cs16[b * 128 + tid - 128]; ceB_l[tid - 128] = ce16[b * 128 + tid - 128]; }
    __syncthreads();
    if (tid < 128) {
        if ((int)csA_l[tid] < (b + 1) * 128 && (int)ceA_l[tid] > b * 128) anyflag = 1;
    }
    __syncthreads();
    if (!anyflag) return;

    const int cg = tid & 15;
    const int rg = tid >> 4;
    int cse[8], cee[8];
    unsigned cp8[8];
#pragma unroll
    for (int e = 0; e < 8; ++e) {
        cse[e] = csB_l[cg * 8 + e]; cee[e] = ceB_l[cg * 8 + e]; cp8[e] = 0u;
    }
    const unsigned short* g = (const unsigned short*)D2pk + (size_t)blockIdx.x * 16384;

#pragma unroll
    for (int k = 0; k < 8; ++k) {
        const int r = k * 16 + rg;
        const int gr = a * 128 + r;
        const int base = b * 128 + cg * 8;
        const int lo_c = min(max((int)csA_l[r] - base, 0), 8);
        const int hi_c = min(max((int)ceA_l[r] - base, 0), 8);
        const unsigned m = (1u << hi_c) - (1u << lo_c);
        const u16x8 v = *(const u16x8*)(g + k * 2048 + tid * 8);
        unsigned rp = 0u;
#pragma unroll
        for (int e = 0; e < 8; ++e) {
            const unsigned hb = v[e];
            rp = max(rp, ((m >> e) & 1u) ? hb : 0u);
            const bool inc = (gr >= cse[e]) && (gr < cee[e]);
            cp8[e] = max(cp8[e], inc ? hb : 0u);
        }
#pragma unroll
        for (int mm = 1; mm < 16; mm <<= 1)
            rp = max(rp, (unsigned)__shfl_xor((int)rp, mm));
        if (cg == 0 && rp) atomicMax(&P32[a * 128 + r], rp);
    }
#pragma unroll
    for (int e = 0; e < 8; ++e) {
#pragma unroll
        for (int mm = 16; mm < 64; mm <<= 1)
            cp8[e] = max(cp8[e], (unsigned)__shfl_xor((int)cp8[e], mm));
    }
    if (lane < 16) {
#pragma unroll
        for (int e = 0; e < 8; ++e) colP_l[wave][cg * 8 + e] = (unsigned short)cp8[e];
    }
    __syncthreads();
    if (tid < 128) {
        const unsigned cp = max(max((unsigned)colP_l[0][tid], (unsigned)colP_l[1][tid]),
                                max((unsigned)colP_l[2][tid], (unsigned)colP_l[3][tid]));
        if (cp) atomicMax(&P32[b * 128 + tid], cp);
    }
}

// Kernel 4: mineNS — single 66 MB sweep computing BOTH hardest-negative (range-
// masked min; mask excludes positives and self) and semi-hard candidate
// min{bits > lob} for row and col anchors. Slot-array commits (unique writes).
__global__ __launch_bounds__(256) void mineNS_kernel(const _Float16* __restrict__ D2pk,
                                                     const unsigned short* __restrict__ cs16,
                                                     const unsigned short* __restrict__ ce16,
                                                     const unsigned* __restrict__ P32,
                                                     unsigned short* __restrict__ NR,
                                                     unsigned short* __restrict__ NC,
                                                     unsigned short* __restrict__ SR,
                                                     unsigned short* __restrict__ SC) {
    __shared__ unsigned short csA_l[128], ceA_l[128], lobA_l[128];
    __shared__ unsigned short csB_l[128], ceB_l[128], lobB_l[128];
    __shared__ unsigned short rowN_l[128], rowS_l[128];
    __shared__ unsigned short colN_l[4][128], colS_l[4][128];
    const int tid = threadIdx.x;
    const int lane = tid & 63, wave = tid >> 6;
    int a, b;
    tri_decode(blockIdx.x, a, b);
    if (tid < 128) {
        csA_l[tid] = cs16[a * 128 + tid];
        ceA_l[tid] = ce16[a * 128 + tid];
        lobA_l[tid] = (unsigned short)P32[a * 128 + tid];
    } else {
        const int t = tid - 128;
        csB_l[t] = cs16[b * 128 + t];
        ceB_l[t] = ce16[b * 128 + t];
        lobB_l[t] = (unsigned short)P32[b * 128 + t];
    }
    __syncthreads();

    const int cg = tid & 15;
    const int rg = tid >> 4;
    unsigned lb[8], cn8[8], sc8[8];
    int cse[8], cee[8];
#pragma unroll
    for (int e = 0; e < 8; ++e) {
        lb[e] = lobB_l[cg * 8 + e];
        cse[e] = csB_l[cg * 8 + e];
        cee[e] = ceB_l[cg * 8 + e];
        cn8[e] = 0xFFFFu; sc8[e] = 0xFFFFu;
    }
    const unsigned short* g = (const unsigned short*)D2pk + (size_t)blockIdx.x * 16384;

#pragma unroll
    for (int k = 0; k < 8; ++k) {
        const int r = k * 16 + rg;
        const int gr = a * 128 + r;
        const unsigned lr = lobA_l[r];
        const int base = b * 128 + cg * 8;
        const int lo_c = min(max((int)csA_l[r] - base, 0), 8);
        const int hi_c = min(max((int)ceA_l[r] - base, 0), 8);
        const unsigned m = (1u << hi_c) - (1u << lo_c);
        const u16x8 v = *(const u16x8*)(g + k * 2048 + tid * 8);
        unsigned rn = 0xFFFFu, sr = 0xFFFFu;
#pragma unroll
        for (int e = 0; e < 8; ++e) {
            const unsigned hb = v[e];
            rn = min(rn, ((m >> e) & 1u) ? 0xFFFFu : hb);
            sr = min(sr, hb > lr ? hb : 0xFFFFu);
            const bool inc = (gr >= cse[e]) && (gr < cee[e]);
            cn8[e] = min(cn8[e], inc ? 0xFFFFu : hb);
            sc8[e] = min(sc8[e], hb > lb[e] ? hb : 0xFFFFu);
        }
#pragma unroll
        for (int mm = 1; mm < 16; mm <<= 1) {
            rn = min(rn, (unsigned)__shfl_xor((int)rn, mm));
            sr = min(sr, (unsigned)__shfl_xor((int)sr, mm));
        }
        if (cg == 0) { rowN_l[r] = (unsigned short)rn; rowS_l[r] = (unsigned short)sr; }
    }
#pragma unroll
    for (int e = 0; e < 8; ++e) {
#pragma unroll
        for (int mm = 16; mm < 64; mm <<= 1) {
            cn8[e] = min(cn8[e], (unsigned)__shfl_xor((int)cn8[e], mm));
            sc8[e] = min(sc8[e], (unsigned)__shfl_xor((int)sc8[e], mm));
        }
    }
    if (lane < 16) {
#pragma unroll
        for (int e = 0; e < 8; ++e) {
            colN_l[wave][cg * 8 + e] = (unsigned short)cn8[e];
            colS_l[wave][cg * 8 + e] = (unsigned short)sc8[e];
        }
    }
    __syncthreads();
    if (tid < 128) {
        NR[(size_t)b * N + a * 128 + tid] = rowN_l[tid];
        SR[(size_t)b * N + a * 128 + tid] = rowS_l[tid];
        const unsigned nm = min(min((unsigned)colN_l[0][tid], (unsigned)colN_l[1][tid]),
                                min((unsigned)colN_l[2][tid], (unsigned)colN_l[3][tid]));
        const unsigned sm = min(min((unsigned)colS_l[0][tid], (unsigned)colS_l[1][tid]),
                                min((unsigned)colS_l[2][tid], (unsigned)colS_l[3][tid]));
        NC[(size_t)a * N + b * 128 + tid] = (unsigned short)nm;
        SC[(size_t)a * N + b * 128 + tid] = (unsigned short)sm;
    }
}

// Kernel 5: foldNS — fold slots, loss from values, block-reduced mean.
__global__ __launch_bounds__(256) void foldNS_kernel(const unsigned short* __restrict__ NR,
                                                     const unsigned short* __restrict__ NC,
                                                     const unsigned short* __restrict__ SR,
                                                     const unsigned short* __restrict__ SC,
                                                     const unsigned* __restrict__ P32,
                                                     float* __restrict__ out) {
    const int tid = threadIdx.x;
    const int i = blockIdx.x * 256 + tid;
    const int ai = i >> 7;
    unsigned nm = 0xFFFFu, sm = 0xFFFFu;
    for (int s = ai; s < 64; ++s) {
        nm = min(nm, (unsigned)NR[(size_t)s * N + i]);
        sm = min(sm, (unsigned)SR[(size_t)s * N + i]);
    }
    for (int s = 0; s <= ai; ++s) {
        nm = min(nm, (unsigned)NC[(size_t)s * N + i]);
        sm = min(sm, (unsigned)SC[(size_t)s * N + i]);
    }
    const float lo = h2f(P32[i]);
    const float dp = sqrtf(lo);
    const float hw = dp + MARGIN;
    const float hi = hw * hw;
    const float smv = h2f(sm);                    // 0xFFFF -> NaN -> fallback
    const float dn2 = (smv < hi) ? smv : h2f(nm);
    float loss = fmaxf(dp - sqrtf(dn2) + MARGIN, 0.0f);
    for (int off = 32; off > 0; off >>= 1) loss += __shfl_down(loss, off);
    __shared__ float red[4];
    const int lane = tid & 63, wave = tid >> 6;
    if (lane == 0) red[wave] = loss;
    __syncthreads();
    if (tid == 0)
        atomicAdd(out, (red[0] + red[1] + red[2] + red[3]) * (1.0f / N));
}

extern "C" void kernel_launch(void* const* d_in, const int* in_sizes, int n_in,
                              void* d_out, int out_size, void* d_ws, size_t ws_size,
                              hipStream_t stream) {
    const float* E = (const float*)d_in[0];
    const int* target = (const int*)d_in[1];
    float* out = (float*)d_out;
    char* ws = (char*)d_ws;

    // Workspace layout (~86 MB):
    unsigned short* Ebf  = (unsigned short*)ws;                         // 16 MB
    float* sq            = (float*)(ws + (size_t)16777216);             // 32 KB
    int* start_g         = (int*)(ws + (size_t)16809984);               // 516 B (pad 1K)
    int* cursor_g        = (int*)(ws + (size_t)16811008);               // 512 B (pad 1K)
    unsigned short* cs16 = (unsigned short*)(ws + (size_t)16812032);    // 16 KB
    unsigned short* ce16 = (unsigned short*)(ws + (size_t)16828416);    // 16 KB
    unsigned* P32        = (unsigned*)(ws + (size_t)16844800);          // 32 KB
    unsigned short* NR   = (unsigned short*)(ws + (size_t)16877568);    // 1 MB
    unsigned short* NC   = (unsigned short*)(ws + (size_t)17926144);    // 1 MB
    unsigned short* SR   = (unsigned short*)(ws + (size_t)18974720);    // 1 MB
    unsigned short* SC   = (unsigned short*)(ws + (size_t)20023296);    // 1 MB
    _Float16* D2pk       = (_Float16*)(ws + (size_t)21071872);          // 65 MB

    hist_kernel<<<1, 256, 0, stream>>>(target, start_g, cursor_g, out);
    scatter_kernel<<<N, 256, 0, stream>>>(E, target, start_g, cursor_g,
                                          Ebf, sq, cs16, ce16, P32);
    gemm_kernel<<<2080, 256, 0, stream>>>(Ebf, sq, D2pk);
    mineP_kernel<<<2080, 256, 0, stream>>>(D2pk, cs16, ce16, P32);
    mineNS_kernel<<<2080, 256, 0, stream>>>(D2pk, cs16, ce16, P32, NR, NC, SR, SC);
    foldNS_kernel<<<N / 256, 256, 0, stream>>>(NR, NC, SR, SC, P32, out);
}